// Round 1
// 321.379 us; speedup vs baseline: 1.2102x; 1.2102x over previous
//
#include <hip/hip_runtime.h>
#include <hip/hip_bf16.h>

#define NEG_SLOPE 0.2f
#define BSH 9                    // 512 dst nodes per bucket
#define BW  (1 << BSH)
#define CH  4096                 // edges per partition round
#define PGRID 256                // workgroups for A0/A1

typedef short short8 __attribute__((ext_vector_type(8)));
typedef float f32x4 __attribute__((ext_vector_type(4)));

// ================= radix CSR build (no global atomics) =================

// A0: per-round bucket histogram. H[r*NBK + b] = #edges of round r in bucket b.
__global__ __launch_bounds__(256) void bucket_hist_kernel(
    const int* __restrict__ adj, int* __restrict__ H, int E, int N, int R, int NBK)
{
    __shared__ int hist[256];
    const int t = threadIdx.x;
    const int ET = E + N;
    for (int r = blockIdx.x; r < R; r += gridDim.x) {
        hist[t] = 0;
        __syncthreads();
        int base = r * CH;
        for (int i = 0; i < CH / 256; ++i) {
            int e = base + i * 256 + t;
            if (e >= ET) break;
            int d = (e < E) ? adj[E + e] : (e - E);
            atomicAdd(&hist[d >> BSH], 1);
        }
        __syncthreads();
        if (t < NBK) H[r * NBK + t] = hist[t];
        __syncthreads();
    }
}

// Per-bucket scan over rounds (196 blocks in parallel):
// S2[r][b] = sum_{r'<r} H[r'][b]  (within-bucket prefix), tot[b] = bucket total.
__global__ __launch_bounds__(256) void scan_rounds_kernel(
    const int* __restrict__ H, int* __restrict__ S2, int* __restrict__ tot,
    int R, int NBK)
{
    __shared__ int part[256];
    const int b = blockIdx.x;
    const int t = threadIdx.x;
    const int C = (R + 255) / 256;
    int r0 = t * C, r1 = min(R, r0 + C);
    int s = 0;
    for (int r = r0; r < r1; ++r) s += H[r * NBK + b];
    part[t] = s;
    __syncthreads();
    for (int off = 1; off < 256; off <<= 1) {
        int v = (t >= off) ? part[t - off] : 0;
        __syncthreads();
        part[t] += v;
        __syncthreads();
    }
    int run = (t > 0) ? part[t - 1] : 0;
    for (int r = r0; r < r1; ++r) {
        int h = H[r * NBK + b];
        S2[r * NBK + b] = run;
        run += h;
    }
    if (t == 255) tot[b] = part[255];
}

// Exclusive scan of bucket totals -> base[b]. One block; NBK <= 256.
__global__ __launch_bounds__(256) void scan_tot_kernel(
    const int* __restrict__ tot, int* __restrict__ base, int NBK)
{
    __shared__ int s[256];
    int t = threadIdx.x;
    int v = (t < NBK) ? tot[t] : 0;
    s[t] = v;
    __syncthreads();
    for (int off = 1; off < 256; off <<= 1) {
        int u = (t >= off) ? s[t - off] : 0;
        __syncthreads();
        s[t] += u;
        __syncthreads();
    }
    if (t < NBK) base[t] = s[t] - v;
}

// A1: scatter edges into bucket-grouped pbuf at precomputed offsets.
// pbuf entry = (src << BSH) | (dst & (BW-1)).  src < 2^17, fits in 23+9 bits.
__global__ __launch_bounds__(256) void partition_kernel(
    const int* __restrict__ adj, const int* __restrict__ S2,
    const int* __restrict__ base, int* __restrict__ pbuf,
    int E, int N, int R, int NBK)
{
    __shared__ int lcur[256];
    const int t = threadIdx.x;
    const int ET = E + N;
    for (int r = blockIdx.x; r < R; r += gridDim.x) {
        if (t < NBK) lcur[t] = base[t] + S2[r * NBK + t];
        __syncthreads();
        int b0 = r * CH;
        for (int i = 0; i < CH / 256; ++i) {
            int e = b0 + i * 256 + t;
            if (e >= ET) break;
            int s, d;
            if (e < E) { d = adj[E + e]; s = adj[e]; }
            else       { s = d = e - E; }
            int b = d >> BSH;
            int pos = atomicAdd(&lcur[b], 1);
            pbuf[pos] = (s << BSH) | (d & (BW - 1));
        }
        __syncthreads();
    }
}

// B: one WG per bucket. LDS hist over 512 local nodes + LDS scan ->
// row_ptr window AND node-grouped col_idx, all inside a ~35KB L2-local window.
__global__ __launch_bounds__(256) void csr_build_kernel(
    const int* __restrict__ base, const int* __restrict__ tot,
    const int* __restrict__ pbuf,
    int* __restrict__ row_ptr, int* __restrict__ col_idx, int E, int N, int NBK)
{
    __shared__ int offA[BW];
    __shared__ int lcur[BW];
    const int b = blockIdx.x;
    const int t = threadIdx.x;
    const int node0 = b << BSH;
    const int nn = min(BW, N - node0);
    const int ET = E + N;
    const int segbeg = base[b];
    const int segend = segbeg + tot[b];

    offA[t] = 0; offA[t + 256] = 0;
    __syncthreads();
    for (int i = segbeg + t; i < segend; i += 256)
        atomicAdd(&offA[pbuf[i] & (BW - 1)], 1);
    __syncthreads();
    // inclusive Hillis-Steele scan over 512 elements (2 per thread)
    for (int off = 1; off < BW; off <<= 1) {
        int i1 = t + 256;
        int v0 = (t >= off) ? offA[t - off] : 0;
        int v1 = (i1 >= off) ? offA[i1 - off] : 0;
        __syncthreads();
        offA[t] += v0; offA[i1] += v1;
        __syncthreads();
    }
    if (t < nn) {
        int ex = t ? offA[t - 1] : 0;
        row_ptr[node0 + t] = segbeg + ex;
        lcur[t] = segbeg + ex;
    }
    int i2 = t + 256;
    if (i2 < nn) {
        int ex = offA[i2 - 1];
        row_ptr[node0 + i2] = segbeg + ex;
        lcur[i2] = segbeg + ex;
    }
    if (b == NBK - 1 && t == 0) row_ptr[N] = ET;
    __syncthreads();
    for (int i = segbeg + t; i < segend; i += 256) {
        int p = pbuf[i];
        int pos = atomicAdd(&lcur[p & (BW - 1)], 1);
        col_idx[pos] = p >> BSH;
    }
}

// ================= dense pieces =================

__device__ __forceinline__ float bf_to_f(unsigned short u)
{
    return __uint_as_float((unsigned)u << 16);
}

__device__ __forceinline__ unsigned short f2bf(float f)
{
    union { __hip_bfloat16 b; unsigned short u; } v;
    v.b = __float2bfloat16(f);
    return v.u;
}

// Pre-pack W into MFMA B-fragment order, bf16.
// Fragment f = s*4 + t  (s = K-step of 32, t = 16-col tile).
// lane l (0..63), elem i (0..7):  k = 32*s + 8*(l/16) + i,  n = 16*t + (l%16).
// NOTE: the A-side packing in gemm_alpha_mfma uses the SAME (l/16, i) -> k map,
// so the result is correct under any HW k-permutation (sum over k is
// permutation-invariant as long as A and B agree).
__global__ __launch_bounds__(256) void prep_wfrag_kernel(
    const float* __restrict__ W, unsigned short* __restrict__ wf, int K)
{
    int total = K * 64;                  // (K/32)*4 frags * 64 lanes * 8 elems
    int idx = blockIdx.x * 256 + threadIdx.x;
    if (idx >= total) return;
    int i = idx & 7;
    int l = (idx >> 3) & 63;
    int f = idx >> 9;
    int s = f >> 2, tt = f & 3;
    int k = 32 * s + 8 * (l >> 4) + i;
    int n = 16 * tt + (l & 15);
    wf[idx] = f2bf(W[k * 64 + n]);
}

// MFMA GEMM + alpha:  h = bf16(X @ W); as[n] = h_f32 . a_src; ad[n] = h_f32 . a_dst.
// 4 waves/block, each wave owns 16 rows x 64 cols (4 col-tiles of 16x16 MFMA).
// X is split hi+lo bf16 (2 MFMAs per tile) -> A-side error ~2^-16 relative;
// only W carries bf16 rounding (~2e-3), same order as the existing bf16 h store.
// No LDS. W fragments live in registers, loaded once per block (grid-stride).
template<int K>
__global__ __launch_bounds__(256) void gemm_alpha_mfma(
    const float* __restrict__ X, const unsigned short* __restrict__ wf,
    const float* __restrict__ a_src, const float* __restrict__ a_dst,
    __hip_bfloat16* __restrict__ h, float* __restrict__ as_, float* __restrict__ ad_,
    int N, int nChunks)
{
    constexpr int S = K / 32;
    const int t = threadIdx.x;
    const int wave = t >> 6, lane = t & 63;
    const int g = lane >> 4, c = lane & 15;

    // B fragments: S*4 frags, 8 bf16 each (4 VGPRs) -> coalesced 16B loads
    short8 bf[S * 4];
#pragma unroll
    for (int f = 0; f < S * 4; ++f)
        bf[f] = *(const short8*)(wf + ((size_t)(f * 64 + lane)) * 8);

    float asr[4], adr[4];
#pragma unroll
    for (int tt = 0; tt < 4; ++tt) {
        asr[tt] = a_src[16 * tt + c];
        adr[tt] = a_dst[16 * tt + c];
    }

    for (int chunk = blockIdx.x; chunk < nChunks; chunk += gridDim.x) {
        const int r0 = chunk * 64 + wave * 16;
        const int arow = r0 + c;                 // row this lane loads for A
        const bool rv = arow < N;
        const float* xr = X + (size_t)arow * K;

        f32x4 acc[4];
#pragma unroll
        for (int tt = 0; tt < 4; ++tt) acc[tt] = (f32x4){0.f, 0.f, 0.f, 0.f};

#pragma unroll
        for (int s = 0; s < S; ++s) {
            // lane reads X[arow][32s + 8g .. 32s + 8g + 7]
            float4 x0 = make_float4(0.f, 0.f, 0.f, 0.f);
            float4 x1 = make_float4(0.f, 0.f, 0.f, 0.f);
            if (rv) {
                const float4* p = (const float4*)(xr + 32 * s + 8 * g);
                x0 = p[0]; x1 = p[1];
            }
            float xs[8] = {x0.x, x0.y, x0.z, x0.w, x1.x, x1.y, x1.z, x1.w};
            // hi = truncate-to-bf16, lo = truncate(x - hi): exact split to ~2^-16
            union { short8 v; unsigned u[4]; } ah, al;
#pragma unroll
            for (int p2 = 0; p2 < 4; ++p2) {
                unsigned u0 = __float_as_uint(xs[2 * p2]);
                unsigned u1 = __float_as_uint(xs[2 * p2 + 1]);
                ah.u[p2] = (u0 >> 16) | (u1 & 0xffff0000u);
                float h0 = __uint_as_float(u0 & 0xffff0000u);
                float h1 = __uint_as_float(u1 & 0xffff0000u);
                unsigned l0 = __float_as_uint(xs[2 * p2] - h0);
                unsigned l1 = __float_as_uint(xs[2 * p2 + 1] - h1);
                al.u[p2] = (l0 >> 16) | (l1 & 0xffff0000u);
            }
#pragma unroll
            for (int tt = 0; tt < 4; ++tt) {
                acc[tt] = __builtin_amdgcn_mfma_f32_16x16x32_bf16(
                    ah.v, bf[s * 4 + tt], acc[tt], 0, 0, 0);
                acc[tt] = __builtin_amdgcn_mfma_f32_16x16x32_bf16(
                    al.v, bf[s * 4 + tt], acc[tt], 0, 0, 0);
            }
        }

        // epilogue: D layout col = c + 16*tt, row = r0 + 4*g + i  [measured m89/m91]
#pragma unroll
        for (int i = 0; i < 4; ++i) {
            const int ri = r0 + 4 * g + i;
            float va = 0.f, vd = 0.f;
#pragma unroll
            for (int tt = 0; tt < 4; ++tt) {
                float v = acc[tt][i];
                va += v * asr[tt];
                vd += v * adr[tt];
                if (ri < N) h[(size_t)ri * 64 + 16 * tt + c] = __float2bfloat16(v);
            }
#pragma unroll
            for (int off = 8; off >= 1; off >>= 1) {
                va += __shfl_xor(va, off, 16);
                vd += __shfl_xor(vd, off, 16);
            }
            if (c == 0 && ri < N) { as_[ri] = va; ad_[ri] = vd; }
        }
    }
}

// Fused softmax+aggregate: one wave per dst node, 16 edges per loop step
// (4 sub-groups of 16 lanes x 4-deep unroll), bf16x4 (8B) loads over the 64-dim row.
__global__ __launch_bounds__(256) void gat_aggregate_kernel(
    const int* __restrict__ row_ptr, const int* __restrict__ col_idx,
    const float* __restrict__ as_, const float* __restrict__ ad_,
    const __hip_bfloat16* __restrict__ h, const float* __restrict__ b,
    float* __restrict__ out, int N, int do_elu)
{
    int node = blockIdx.x * 4 + (threadIdx.x >> 6);
    int lane = threadIdx.x & 63;
    int sub = lane >> 4, q = lane & 15;
    if (node >= N) return;
    int beg = row_ptr[node], end = row_ptr[node + 1];
    float ad = ad_[node];
    float4 acc = make_float4(0.f, 0.f, 0.f, 0.f);
    float psum = 0.f;
    const ushort4* hb = (const ushort4*)h;
    for (int i = beg; i < end; i += 16) {
        int e0 = i + sub, e1 = i + 4 + sub, e2 = i + 8 + sub, e3 = i + 12 + sub;
        bool v0 = e0 < end, v1 = e1 < end, v2 = e2 < end, v3 = e3 < end;
        int s0 = col_idx[v0 ? e0 : end - 1];
        int s1 = col_idx[v1 ? e1 : end - 1];
        int s2 = col_idx[v2 ? e2 : end - 1];
        int s3 = col_idx[v3 ? e3 : end - 1];
        float x0 = as_[s0] + ad, x1 = as_[s1] + ad;
        float x2 = as_[s2] + ad, x3 = as_[s3] + ad;
        ushort4 u0 = hb[(size_t)s0 * 16 + q];
        ushort4 u1 = hb[(size_t)s1 * 16 + q];
        ushort4 u2 = hb[(size_t)s2 * 16 + q];
        ushort4 u3 = hb[(size_t)s3 * 16 + q];
        x0 = x0 > 0.f ? x0 : NEG_SLOPE * x0;
        x1 = x1 > 0.f ? x1 : NEG_SLOPE * x1;
        x2 = x2 > 0.f ? x2 : NEG_SLOPE * x2;
        x3 = x3 > 0.f ? x3 : NEG_SLOPE * x3;
        float p0 = v0 ? __expf(x0) : 0.f;
        float p1 = v1 ? __expf(x1) : 0.f;
        float p2 = v2 ? __expf(x2) : 0.f;
        float p3 = v3 ? __expf(x3) : 0.f;
        psum += (p0 + p1) + (p2 + p3);
        acc.x += p0 * bf_to_f(u0.x) + p1 * bf_to_f(u1.x) + p2 * bf_to_f(u2.x) + p3 * bf_to_f(u3.x);
        acc.y += p0 * bf_to_f(u0.y) + p1 * bf_to_f(u1.y) + p2 * bf_to_f(u2.y) + p3 * bf_to_f(u3.y);
        acc.z += p0 * bf_to_f(u0.z) + p1 * bf_to_f(u1.z) + p2 * bf_to_f(u2.z) + p3 * bf_to_f(u3.z);
        acc.w += p0 * bf_to_f(u0.w) + p1 * bf_to_f(u1.w) + p2 * bf_to_f(u2.w) + p3 * bf_to_f(u3.w);
    }
#pragma unroll
    for (int off = 16; off <= 32; off <<= 1) {
        acc.x += __shfl_xor(acc.x, off, 64);
        acc.y += __shfl_xor(acc.y, off, 64);
        acc.z += __shfl_xor(acc.z, off, 64);
        acc.w += __shfl_xor(acc.w, off, 64);
        psum  += __shfl_xor(psum,  off, 64);
    }
    if (sub == 0) {
        float inv = 1.f / psum;
        float4 bb = ((const float4*)b)[q];
        float4 v;
        v.x = acc.x * inv + bb.x;
        v.y = acc.y * inv + bb.y;
        v.z = acc.z * inv + bb.z;
        v.w = acc.w * inv + bb.w;
        if (do_elu) {
            v.x = v.x > 0.f ? v.x : (__expf(v.x) - 1.f);
            v.y = v.y > 0.f ? v.y : (__expf(v.y) - 1.f);
            v.z = v.z > 0.f ? v.z : (__expf(v.z) - 1.f);
            v.w = v.w > 0.f ? v.w : (__expf(v.w) - 1.f);
        }
        ((float4*)(out + (size_t)node * 64))[q] = v;
    }
}

// logits[n][c] = x[n]·cW[:,c] + cb[c]
__global__ __launch_bounds__(256) void classifier_kernel(
    const float* __restrict__ x, const float* __restrict__ cw,
    const float* __restrict__ cb, float* __restrict__ out, int N)
{
    int i = blockIdx.x * blockDim.x + threadIdx.x;
    if (i >= N * 16) return;
    int n = i >> 4, c = i & 15;
    const float4* xr = (const float4*)(x + (size_t)n * 64);
    float acc = cb[c];
#pragma unroll
    for (int j4 = 0; j4 < 16; ++j4) {
        float4 xv = xr[j4];
        acc += xv.x * cw[(j4 * 4 + 0) * 16 + c];
        acc += xv.y * cw[(j4 * 4 + 1) * 16 + c];
        acc += xv.z * cw[(j4 * 4 + 2) * 16 + c];
        acc += xv.w * cw[(j4 * 4 + 3) * 16 + c];
    }
    out[i] = acc;
}

extern "C" void kernel_launch(void* const* d_in, const int* in_sizes, int n_in,
                              void* d_out, int out_size, void* d_ws, size_t ws_size,
                              hipStream_t stream)
{
    const float* X    = (const float*)d_in[0];
    const int*   adj  = (const int*)d_in[1];
    const float* W1   = (const float*)d_in[2];
    const float* a_s1 = (const float*)d_in[3];
    const float* a_d1 = (const float*)d_in[4];
    const float* b1   = (const float*)d_in[5];
    const float* W2   = (const float*)d_in[6];
    const float* a_s2 = (const float*)d_in[7];
    const float* a_d2 = (const float*)d_in[8];
    const float* b2   = (const float*)d_in[9];
    const float* cW   = (const float*)d_in[10];
    const float* cb   = (const float*)d_in[11];

    const int N   = in_sizes[0] / 128;
    const int E   = in_sizes[1] / 2;
    const int ET  = E + N;
    const int R   = (ET + CH - 1) / CH;           // partition rounds
    const int NBK = (N + BW - 1) >> BSH;          // buckets (<=256)

    __hip_bfloat16* A = (__hip_bfloat16*)d_ws;        // h (bf16), N*64
    float* B       = (float*)(A + (size_t)N * 64);    // layer1 x, N*64 f32
    float* asb     = B + (size_t)N * 64;              // N
    float* adb     = asb + N;                         // N
    int*   row_ptr = (int*)(adb + N);                 // N+1
    int*   col_idx = row_ptr + (N + 1);               // ET
    int*   pbuf    = col_idx + ET;                    // ET
    int*   H       = pbuf + ET;                       // R*NBK
    int*   S2      = H + R * NBK;                     // R*NBK
    int*   tot     = S2 + R * NBK;                    // NBK
    int*   base    = tot + NBK;                       // NBK

    // W fragment buffers alias pbuf (dead after csr_build; preps run after it)
    uintptr_t wp = ((uintptr_t)pbuf + 15) & ~(uintptr_t)15;
    unsigned short* wf1 = (unsigned short*)wp;        // 128*64 ushort = 16KB
    unsigned short* wf2 = wf1 + 128 * 64;             // 64*64 ushort = 8KB

    const int T = 256;
    const int aggBlocks  = (N + 3) / 4;
    const int nChunks    = (N + 63) / 64;
    const int gemmBlocks = nChunks < 512 ? nChunks : 512;

    // ---- radix CSR build (once, reused by both layers) ----
    bucket_hist_kernel<<<PGRID, T, 0, stream>>>(adj, H, E, N, R, NBK);
    scan_rounds_kernel<<<NBK, T, 0, stream>>>(H, S2, tot, R, NBK);
    scan_tot_kernel<<<1, T, 0, stream>>>(tot, base, NBK);
    partition_kernel<<<PGRID, T, 0, stream>>>(adj, S2, base, pbuf, E, N, R, NBK);
    csr_build_kernel<<<NBK, T, 0, stream>>>(base, tot, pbuf, row_ptr, col_idx, E, N, NBK);

    // ---- pack W fragments (after csr_build: pbuf space is dead now) ----
    prep_wfrag_kernel<<<(128 * 64 + 255) / 256, T, 0, stream>>>(W1, wf1, 128);
    prep_wfrag_kernel<<<(64 * 64 + 255) / 256, T, 0, stream>>>(W2, wf2, 64);

    // ---- layer 1 ----
    gemm_alpha_mfma<128><<<gemmBlocks, T, 0, stream>>>(
        X, wf1, a_s1, a_d1, A, asb, adb, N, nChunks);
    gat_aggregate_kernel<<<aggBlocks, T, 0, stream>>>(
        row_ptr, col_idx, asb, adb, A, b1, B, N, 1);

    // ---- layer 2 (x written straight into d_out tail) ----
    float* out  = (float*)d_out;
    float* xout = out + (size_t)N * 16;
    gemm_alpha_mfma<64><<<gemmBlocks, T, 0, stream>>>(
        B, wf2, a_s2, a_d2, A, asb, adb, N, nChunks);
    gat_aggregate_kernel<<<aggBlocks, T, 0, stream>>>(
        row_ptr, col_idx, asb, adb, A, b2, xout, N, 0);

    // ---- classifier ----
    classifier_kernel<<<(N * 16 + T - 1) / T, T, 0, stream>>>(
        xout, cW, cb, out, N);
}

// Round 2
// 316.997 us; speedup vs baseline: 1.2269x; 1.0138x over previous
//
#include <hip/hip_runtime.h>
#include <hip/hip_bf16.h>

#define NEG_SLOPE 0.2f
#define BSH 9                    // 512 dst nodes per bucket
#define BW  (1 << BSH)
#define CH  4096                 // edges per partition round
#define PGRID 256                // workgroups for A0/A1

typedef short short8 __attribute__((ext_vector_type(8)));
typedef float f32x4 __attribute__((ext_vector_type(4)));

// ================= radix CSR build (no global atomics) =================

// A0: per-round bucket histogram. H[r*NBK + b] = #edges of round r in bucket b.
__global__ __launch_bounds__(256) void bucket_hist_kernel(
    const int* __restrict__ adj, int* __restrict__ H, int E, int N, int R, int NBK)
{
    __shared__ int hist[256];
    const int t = threadIdx.x;
    const int ET = E + N;
    for (int r = blockIdx.x; r < R; r += gridDim.x) {
        hist[t] = 0;
        __syncthreads();
        int base = r * CH;
        for (int i = 0; i < CH / 256; ++i) {
            int e = base + i * 256 + t;
            if (e >= ET) break;
            int d = (e < E) ? adj[E + e] : (e - E);
            atomicAdd(&hist[d >> BSH], 1);
        }
        __syncthreads();
        if (t < NBK) H[r * NBK + t] = hist[t];
        __syncthreads();
    }
}

// Per-bucket scan over rounds (196 blocks in parallel):
// S2[r][b] = sum_{r'<r} H[r'][b]  (within-bucket prefix), tot[b] = bucket total.
__global__ __launch_bounds__(256) void scan_rounds_kernel(
    const int* __restrict__ H, int* __restrict__ S2, int* __restrict__ tot,
    int R, int NBK)
{
    __shared__ int part[256];
    const int b = blockIdx.x;
    const int t = threadIdx.x;
    const int C = (R + 255) / 256;
    int r0 = t * C, r1 = min(R, r0 + C);
    int s = 0;
    for (int r = r0; r < r1; ++r) s += H[r * NBK + b];
    part[t] = s;
    __syncthreads();
    for (int off = 1; off < 256; off <<= 1) {
        int v = (t >= off) ? part[t - off] : 0;
        __syncthreads();
        part[t] += v;
        __syncthreads();
    }
    int run = (t > 0) ? part[t - 1] : 0;
    for (int r = r0; r < r1; ++r) {
        int h = H[r * NBK + b];
        S2[r * NBK + b] = run;
        run += h;
    }
    if (t == 255) tot[b] = part[255];
}

// Exclusive scan of bucket totals -> base[b]. One block; NBK <= 256.
__global__ __launch_bounds__(256) void scan_tot_kernel(
    const int* __restrict__ tot, int* __restrict__ base, int NBK)
{
    __shared__ int s[256];
    int t = threadIdx.x;
    int v = (t < NBK) ? tot[t] : 0;
    s[t] = v;
    __syncthreads();
    for (int off = 1; off < 256; off <<= 1) {
        int u = (t >= off) ? s[t - off] : 0;
        __syncthreads();
        s[t] += u;
        __syncthreads();
    }
    if (t < NBK) base[t] = s[t] - v;
}

// A1: scatter edges into bucket-grouped pbuf at precomputed offsets.
// pbuf entry = (src << BSH) | (dst & (BW-1)).  src < 2^17, fits in 23+9 bits.
__global__ __launch_bounds__(256) void partition_kernel(
    const int* __restrict__ adj, const int* __restrict__ S2,
    const int* __restrict__ base, int* __restrict__ pbuf,
    int E, int N, int R, int NBK)
{
    __shared__ int lcur[256];
    const int t = threadIdx.x;
    const int ET = E + N;
    for (int r = blockIdx.x; r < R; r += gridDim.x) {
        if (t < NBK) lcur[t] = base[t] + S2[r * NBK + t];
        __syncthreads();
        int b0 = r * CH;
        for (int i = 0; i < CH / 256; ++i) {
            int e = b0 + i * 256 + t;
            if (e >= ET) break;
            int s, d;
            if (e < E) { d = adj[E + e]; s = adj[e]; }
            else       { s = d = e - E; }
            int b = d >> BSH;
            int pos = atomicAdd(&lcur[b], 1);
            pbuf[pos] = (s << BSH) | (d & (BW - 1));
        }
        __syncthreads();
    }
}

// B: one WG per bucket. LDS hist over 512 local nodes + LDS scan ->
// row_ptr window AND node-grouped col_idx, all inside a ~35KB L2-local window.
__global__ __launch_bounds__(256) void csr_build_kernel(
    const int* __restrict__ base, const int* __restrict__ tot,
    const int* __restrict__ pbuf,
    int* __restrict__ row_ptr, int* __restrict__ col_idx, int E, int N, int NBK)
{
    __shared__ int offA[BW];
    __shared__ int lcur[BW];
    const int b = blockIdx.x;
    const int t = threadIdx.x;
    const int node0 = b << BSH;
    const int nn = min(BW, N - node0);
    const int ET = E + N;
    const int segbeg = base[b];
    const int segend = segbeg + tot[b];

    offA[t] = 0; offA[t + 256] = 0;
    __syncthreads();
    for (int i = segbeg + t; i < segend; i += 256)
        atomicAdd(&offA[pbuf[i] & (BW - 1)], 1);
    __syncthreads();
    // inclusive Hillis-Steele scan over 512 elements (2 per thread)
    for (int off = 1; off < BW; off <<= 1) {
        int i1 = t + 256;
        int v0 = (t >= off) ? offA[t - off] : 0;
        int v1 = (i1 >= off) ? offA[i1 - off] : 0;
        __syncthreads();
        offA[t] += v0; offA[i1] += v1;
        __syncthreads();
    }
    if (t < nn) {
        int ex = t ? offA[t - 1] : 0;
        row_ptr[node0 + t] = segbeg + ex;
        lcur[t] = segbeg + ex;
    }
    int i2 = t + 256;
    if (i2 < nn) {
        int ex = offA[i2 - 1];
        row_ptr[node0 + i2] = segbeg + ex;
        lcur[i2] = segbeg + ex;
    }
    if (b == NBK - 1 && t == 0) row_ptr[N] = ET;
    __syncthreads();
    for (int i = segbeg + t; i < segend; i += 256) {
        int p = pbuf[i];
        int pos = atomicAdd(&lcur[p & (BW - 1)], 1);
        col_idx[pos] = p >> BSH;
    }
}

// ================= dense pieces =================

__device__ __forceinline__ float bf_to_f(unsigned short u)
{
    return __uint_as_float((unsigned)u << 16);
}

__device__ __forceinline__ unsigned short f2bf(float f)
{
    union { __hip_bfloat16 b; unsigned short u; } v;
    v.b = __float2bfloat16(f);
    return v.u;
}

// Pre-pack W into MFMA B-fragment order, bf16.
// Fragment f = s*4 + t  (s = K-step of 32, t = 16-col tile).
// lane l (0..63), elem i (0..7):  k = 32*s + 8*(l/16) + i,  n = 16*t + (l%16).
__global__ __launch_bounds__(256) void prep_wfrag_kernel(
    const float* __restrict__ W, unsigned short* __restrict__ wf, int K)
{
    int total = K * 64;                  // (K/32)*4 frags * 64 lanes * 8 elems
    int idx = blockIdx.x * 256 + threadIdx.x;
    if (idx >= total) return;
    int i = idx & 7;
    int l = (idx >> 3) & 63;
    int f = idx >> 9;
    int s = f >> 2, tt = f & 3;
    int k = 32 * s + 8 * (l >> 4) + i;
    int n = 16 * tt + (l & 15);
    wf[idx] = f2bf(W[k * 64 + n]);
}

// MFMA GEMM + alpha:  h = bf16(X @ W); as[n] = h_f32 . a_src; ad[n] = h_f32 . a_dst.
// 4 waves/block, each wave owns 16 rows x 64 cols (4 col-tiles of 16x16 MFMA).
// X is split hi+lo bf16 (2 MFMAs per tile) -> A-side error ~2^-16 relative;
// only W carries bf16 rounding (~2e-3), same order as the existing bf16 h store.
template<int K>
__global__ __launch_bounds__(256) void gemm_alpha_mfma(
    const float* __restrict__ X, const unsigned short* __restrict__ wf,
    const float* __restrict__ a_src, const float* __restrict__ a_dst,
    __hip_bfloat16* __restrict__ h, float* __restrict__ as_, float* __restrict__ ad_,
    int N, int nChunks)
{
    constexpr int S = K / 32;
    const int t = threadIdx.x;
    const int wave = t >> 6, lane = t & 63;
    const int g = lane >> 4, c = lane & 15;

    // B fragments: S*4 frags, 8 bf16 each (4 VGPRs) -> coalesced 16B loads
    short8 bf[S * 4];
#pragma unroll
    for (int f = 0; f < S * 4; ++f)
        bf[f] = *(const short8*)(wf + ((size_t)(f * 64 + lane)) * 8);

    float asr[4], adr[4];
#pragma unroll
    for (int tt = 0; tt < 4; ++tt) {
        asr[tt] = a_src[16 * tt + c];
        adr[tt] = a_dst[16 * tt + c];
    }

    for (int chunk = blockIdx.x; chunk < nChunks; chunk += gridDim.x) {
        const int r0 = chunk * 64 + wave * 16;
        const int arow = r0 + c;                 // row this lane loads for A
        const bool rv = arow < N;
        const float* xr = X + (size_t)arow * K;

        f32x4 acc[4];
#pragma unroll
        for (int tt = 0; tt < 4; ++tt) acc[tt] = (f32x4){0.f, 0.f, 0.f, 0.f};

#pragma unroll
        for (int s = 0; s < S; ++s) {
            // lane reads X[arow][32s + 8g .. 32s + 8g + 7]
            float4 x0 = make_float4(0.f, 0.f, 0.f, 0.f);
            float4 x1 = make_float4(0.f, 0.f, 0.f, 0.f);
            if (rv) {
                const float4* p = (const float4*)(xr + 32 * s + 8 * g);
                x0 = p[0]; x1 = p[1];
            }
            float xs[8] = {x0.x, x0.y, x0.z, x0.w, x1.x, x1.y, x1.z, x1.w};
            // hi = truncate-to-bf16, lo = truncate(x - hi): exact split to ~2^-16
            union { short8 v; unsigned u[4]; } ah, al;
#pragma unroll
            for (int p2 = 0; p2 < 4; ++p2) {
                unsigned u0 = __float_as_uint(xs[2 * p2]);
                unsigned u1 = __float_as_uint(xs[2 * p2 + 1]);
                ah.u[p2] = (u0 >> 16) | (u1 & 0xffff0000u);
                float h0 = __uint_as_float(u0 & 0xffff0000u);
                float h1 = __uint_as_float(u1 & 0xffff0000u);
                unsigned l0 = __float_as_uint(xs[2 * p2] - h0);
                unsigned l1 = __float_as_uint(xs[2 * p2 + 1] - h1);
                al.u[p2] = (l0 >> 16) | (l1 & 0xffff0000u);
            }
#pragma unroll
            for (int tt = 0; tt < 4; ++tt) {
                acc[tt] = __builtin_amdgcn_mfma_f32_16x16x32_bf16(
                    ah.v, bf[s * 4 + tt], acc[tt], 0, 0, 0);
                acc[tt] = __builtin_amdgcn_mfma_f32_16x16x32_bf16(
                    al.v, bf[s * 4 + tt], acc[tt], 0, 0, 0);
            }
        }

        // epilogue: D layout col = c + 16*tt, row = r0 + 4*g + i  [measured m89/m91]
#pragma unroll
        for (int i = 0; i < 4; ++i) {
            const int ri = r0 + 4 * g + i;
            float va = 0.f, vd = 0.f;
#pragma unroll
            for (int tt = 0; tt < 4; ++tt) {
                float v = acc[tt][i];
                va += v * asr[tt];
                vd += v * adr[tt];
                if (ri < N) h[(size_t)ri * 64 + 16 * tt + c] = __float2bfloat16(v);
            }
#pragma unroll
            for (int off = 8; off >= 1; off >>= 1) {
                va += __shfl_xor(va, off, 16);
                vd += __shfl_xor(vd, off, 16);
            }
            if (c == 0 && ri < N) { as_[ri] = va; ad_[ri] = vd; }
        }
    }
}

// Fused softmax+aggregate: one wave per dst node, 16 edges per loop step.
// This round: 32-bit saddr-friendly addressing (1 shift per gather instead of
// 64-bit mul/add chains), peeled main loop with zero validity logic, and
// leaky_relu as fmaxf(x, 0.2x) (valid for slope < 1).
__global__ __launch_bounds__(256) void gat_aggregate_kernel(
    const int* __restrict__ row_ptr, const int* __restrict__ col_idx,
    const float* __restrict__ as_, const float* __restrict__ ad_,
    const __hip_bfloat16* __restrict__ h, const float* __restrict__ b,
    float* __restrict__ out, int N, int do_elu)
{
    int node = blockIdx.x * 4 + (threadIdx.x >> 6);
    int lane = threadIdx.x & 63;
    int sub = lane >> 4, q = lane & 15;
    if (node >= N) return;
    int beg = row_ptr[node], end = row_ptr[node + 1];
    float ad = ad_[node];
    float4 acc = make_float4(0.f, 0.f, 0.f, 0.f);
    float psum = 0.f;

    const char* cbp = (const char*)col_idx;
    const char* abp = (const char*)as_;
    const char* hbp = (const char*)h;
    const unsigned qb = (unsigned)q * 8u;

    int base = beg;
    unsigned co = (unsigned)(beg + sub) * 4u;
    // main loop: full 16-edge windows, no bounds checks anywhere
    for (; base + 16 <= end; base += 16, co += 64u) {
        int s0 = *(const int*)(cbp + co);
        int s1 = *(const int*)(cbp + (co + 16u));
        int s2 = *(const int*)(cbp + (co + 32u));
        int s3 = *(const int*)(cbp + (co + 48u));
        float x0 = *(const float*)(abp + ((unsigned)s0 << 2)) + ad;
        float x1 = *(const float*)(abp + ((unsigned)s1 << 2)) + ad;
        float x2 = *(const float*)(abp + ((unsigned)s2 << 2)) + ad;
        float x3 = *(const float*)(abp + ((unsigned)s3 << 2)) + ad;
        ushort4 u0 = *(const ushort4*)(hbp + (((unsigned)s0 << 7) + qb));
        ushort4 u1 = *(const ushort4*)(hbp + (((unsigned)s1 << 7) + qb));
        ushort4 u2 = *(const ushort4*)(hbp + (((unsigned)s2 << 7) + qb));
        ushort4 u3 = *(const ushort4*)(hbp + (((unsigned)s3 << 7) + qb));
        x0 = fmaxf(x0, NEG_SLOPE * x0);
        x1 = fmaxf(x1, NEG_SLOPE * x1);
        x2 = fmaxf(x2, NEG_SLOPE * x2);
        x3 = fmaxf(x3, NEG_SLOPE * x3);
        float p0 = __expf(x0);
        float p1 = __expf(x1);
        float p2 = __expf(x2);
        float p3 = __expf(x3);
        psum += (p0 + p1) + (p2 + p3);
        acc.x += p0 * bf_to_f(u0.x) + p1 * bf_to_f(u1.x) + p2 * bf_to_f(u2.x) + p3 * bf_to_f(u3.x);
        acc.y += p0 * bf_to_f(u0.y) + p1 * bf_to_f(u1.y) + p2 * bf_to_f(u2.y) + p3 * bf_to_f(u3.y);
        acc.z += p0 * bf_to_f(u0.z) + p1 * bf_to_f(u1.z) + p2 * bf_to_f(u2.z) + p3 * bf_to_f(u3.z);
        acc.w += p0 * bf_to_f(u0.w) + p1 * bf_to_f(u1.w) + p2 * bf_to_f(u2.w) + p3 * bf_to_f(u3.w);
    }
    // tail: one masked window per node
    if (base < end) {
        int e0 = base + sub, e1 = base + 4 + sub, e2 = base + 8 + sub, e3 = base + 12 + sub;
        bool v0 = e0 < end, v1 = e1 < end, v2 = e2 < end, v3 = e3 < end;
        unsigned c0 = (unsigned)(v0 ? e0 : end - 1) * 4u;
        unsigned c1 = (unsigned)(v1 ? e1 : end - 1) * 4u;
        unsigned c2 = (unsigned)(v2 ? e2 : end - 1) * 4u;
        unsigned c3 = (unsigned)(v3 ? e3 : end - 1) * 4u;
        int s0 = *(const int*)(cbp + c0);
        int s1 = *(const int*)(cbp + c1);
        int s2 = *(const int*)(cbp + c2);
        int s3 = *(const int*)(cbp + c3);
        float x0 = *(const float*)(abp + ((unsigned)s0 << 2)) + ad;
        float x1 = *(const float*)(abp + ((unsigned)s1 << 2)) + ad;
        float x2 = *(const float*)(abp + ((unsigned)s2 << 2)) + ad;
        float x3 = *(const float*)(abp + ((unsigned)s3 << 2)) + ad;
        ushort4 u0 = *(const ushort4*)(hbp + (((unsigned)s0 << 7) + qb));
        ushort4 u1 = *(const ushort4*)(hbp + (((unsigned)s1 << 7) + qb));
        ushort4 u2 = *(const ushort4*)(hbp + (((unsigned)s2 << 7) + qb));
        ushort4 u3 = *(const ushort4*)(hbp + (((unsigned)s3 << 7) + qb));
        x0 = fmaxf(x0, NEG_SLOPE * x0);
        x1 = fmaxf(x1, NEG_SLOPE * x1);
        x2 = fmaxf(x2, NEG_SLOPE * x2);
        x3 = fmaxf(x3, NEG_SLOPE * x3);
        float p0 = v0 ? __expf(x0) : 0.f;
        float p1 = v1 ? __expf(x1) : 0.f;
        float p2 = v2 ? __expf(x2) : 0.f;
        float p3 = v3 ? __expf(x3) : 0.f;
        psum += (p0 + p1) + (p2 + p3);
        acc.x += p0 * bf_to_f(u0.x) + p1 * bf_to_f(u1.x) + p2 * bf_to_f(u2.x) + p3 * bf_to_f(u3.x);
        acc.y += p0 * bf_to_f(u0.y) + p1 * bf_to_f(u1.y) + p2 * bf_to_f(u2.y) + p3 * bf_to_f(u3.y);
        acc.z += p0 * bf_to_f(u0.z) + p1 * bf_to_f(u1.z) + p2 * bf_to_f(u2.z) + p3 * bf_to_f(u3.z);
        acc.w += p0 * bf_to_f(u0.w) + p1 * bf_to_f(u1.w) + p2 * bf_to_f(u2.w) + p3 * bf_to_f(u3.w);
    }
#pragma unroll
    for (int off = 16; off <= 32; off <<= 1) {
        acc.x += __shfl_xor(acc.x, off, 64);
        acc.y += __shfl_xor(acc.y, off, 64);
        acc.z += __shfl_xor(acc.z, off, 64);
        acc.w += __shfl_xor(acc.w, off, 64);
        psum  += __shfl_xor(psum,  off, 64);
    }
    if (sub == 0) {
        float inv = 1.f / psum;
        float4 bb = ((const float4*)b)[q];
        float4 v;
        v.x = acc.x * inv + bb.x;
        v.y = acc.y * inv + bb.y;
        v.z = acc.z * inv + bb.z;
        v.w = acc.w * inv + bb.w;
        if (do_elu) {
            v.x = v.x > 0.f ? v.x : (__expf(v.x) - 1.f);
            v.y = v.y > 0.f ? v.y : (__expf(v.y) - 1.f);
            v.z = v.z > 0.f ? v.z : (__expf(v.z) - 1.f);
            v.w = v.w > 0.f ? v.w : (__expf(v.w) - 1.f);
        }
        ((float4*)(out + (size_t)node * 64))[q] = v;
    }
}

// logits[n][c] = x[n]·cW[:,c] + cb[c]
__global__ __launch_bounds__(256) void classifier_kernel(
    const float* __restrict__ x, const float* __restrict__ cw,
    const float* __restrict__ cb, float* __restrict__ out, int N)
{
    int i = blockIdx.x * blockDim.x + threadIdx.x;
    if (i >= N * 16) return;
    int n = i >> 4, c = i & 15;
    const float4* xr = (const float4*)(x + (size_t)n * 64);
    float acc = cb[c];
#pragma unroll
    for (int j4 = 0; j4 < 16; ++j4) {
        float4 xv = xr[j4];
        acc += xv.x * cw[(j4 * 4 + 0) * 16 + c];
        acc += xv.y * cw[(j4 * 4 + 1) * 16 + c];
        acc += xv.z * cw[(j4 * 4 + 2) * 16 + c];
        acc += xv.w * cw[(j4 * 4 + 3) * 16 + c];
    }
    out[i] = acc;
}

extern "C" void kernel_launch(void* const* d_in, const int* in_sizes, int n_in,
                              void* d_out, int out_size, void* d_ws, size_t ws_size,
                              hipStream_t stream)
{
    const float* X    = (const float*)d_in[0];
    const int*   adj  = (const int*)d_in[1];
    const float* W1   = (const float*)d_in[2];
    const float* a_s1 = (const float*)d_in[3];
    const float* a_d1 = (const float*)d_in[4];
    const float* b1   = (const float*)d_in[5];
    const float* W2   = (const float*)d_in[6];
    const float* a_s2 = (const float*)d_in[7];
    const float* a_d2 = (const float*)d_in[8];
    const float* b2   = (const float*)d_in[9];
    const float* cW   = (const float*)d_in[10];
    const float* cb   = (const float*)d_in[11];

    const int N   = in_sizes[0] / 128;
    const int E   = in_sizes[1] / 2;
    const int ET  = E + N;
    const int R   = (ET + CH - 1) / CH;           // partition rounds
    const int NBK = (N + BW - 1) >> BSH;          // buckets (<=256)

    __hip_bfloat16* A = (__hip_bfloat16*)d_ws;        // h (bf16), N*64
    float* B       = (float*)(A + (size_t)N * 64);    // layer1 x, N*64 f32
    float* asb     = B + (size_t)N * 64;              // N
    float* adb     = asb + N;                         // N
    int*   row_ptr = (int*)(adb + N);                 // N+1
    int*   col_idx = row_ptr + (N + 1);               // ET
    int*   pbuf    = col_idx + ET;                    // ET
    int*   H       = pbuf + ET;                       // R*NBK
    int*   S2      = H + R * NBK;                     // R*NBK
    int*   tot     = S2 + R * NBK;                    // NBK
    int*   base    = tot + NBK;                       // NBK

    // W fragment buffers alias pbuf (dead after csr_build; preps run after it)
    uintptr_t wp = ((uintptr_t)pbuf + 15) & ~(uintptr_t)15;
    unsigned short* wf1 = (unsigned short*)wp;        // 128*64 ushort = 16KB
    unsigned short* wf2 = wf1 + 128 * 64;             // 64*64 ushort = 8KB

    const int T = 256;
    const int aggBlocks  = (N + 3) / 4;
    const int nChunks    = (N + 63) / 64;
    const int gemmBlocks = nChunks < 512 ? nChunks : 512;

    // ---- radix CSR build (once, reused by both layers) ----
    bucket_hist_kernel<<<PGRID, T, 0, stream>>>(adj, H, E, N, R, NBK);
    scan_rounds_kernel<<<NBK, T, 0, stream>>>(H, S2, tot, R, NBK);
    scan_tot_kernel<<<1, T, 0, stream>>>(tot, base, NBK);
    partition_kernel<<<PGRID, T, 0, stream>>>(adj, S2, base, pbuf, E, N, R, NBK);
    csr_build_kernel<<<NBK, T, 0, stream>>>(base, tot, pbuf, row_ptr, col_idx, E, N, NBK);

    // ---- pack W fragments (after csr_build: pbuf space is dead now) ----
    prep_wfrag_kernel<<<(128 * 64 + 255) / 256, T, 0, stream>>>(W1, wf1, 128);
    prep_wfrag_kernel<<<(64 * 64 + 255) / 256, T, 0, stream>>>(W2, wf2, 64);

    // ---- layer 1 ----
    gemm_alpha_mfma<128><<<gemmBlocks, T, 0, stream>>>(
        X, wf1, a_s1, a_d1, A, asb, adb, N, nChunks);
    gat_aggregate_kernel<<<aggBlocks, T, 0, stream>>>(
        row_ptr, col_idx, asb, adb, A, b1, B, N, 1);

    // ---- layer 2 (x written straight into d_out tail) ----
    float* out  = (float*)d_out;
    float* xout = out + (size_t)N * 16;
    gemm_alpha_mfma<64><<<gemmBlocks, T, 0, stream>>>(
        B, wf2, a_s2, a_d2, A, asb, adb, N, nChunks);
    gat_aggregate_kernel<<<aggBlocks, T, 0, stream>>>(
        row_ptr, col_idx, asb, adb, A, b2, xout, N, 0);

    // ---- classifier ----
    classifier_kernel<<<(N * 16 + T - 1) / T, T, 0, stream>>>(
        xout, cW, cb, out, N);
}

// Round 3
// 312.303 us; speedup vs baseline: 1.2453x; 1.0150x over previous
//
#include <hip/hip_runtime.h>
#include <hip/hip_bf16.h>

#define NEG_SLOPE 0.2f
#define LOG2E 1.4426950408889634f
#define BSH 9                    // 512 dst nodes per bucket
#define BW  (1 << BSH)
#define CH  4096                 // edges per partition round
#define PGRID 256                // workgroups for A0/A1

typedef short short8 __attribute__((ext_vector_type(8)));
typedef float f32x4 __attribute__((ext_vector_type(4)));

// ================= radix CSR build (no global atomics) =================

// A0: per-round bucket histogram. H[r*NBK + b] = #edges of round r in bucket b.
__global__ __launch_bounds__(256) void bucket_hist_kernel(
    const int* __restrict__ adj, int* __restrict__ H, int E, int N, int R, int NBK)
{
    __shared__ int hist[256];
    const int t = threadIdx.x;
    const int ET = E + N;
    for (int r = blockIdx.x; r < R; r += gridDim.x) {
        hist[t] = 0;
        __syncthreads();
        int base = r * CH;
        for (int i = 0; i < CH / 256; ++i) {
            int e = base + i * 256 + t;
            if (e >= ET) break;
            int d = (e < E) ? adj[E + e] : (e - E);
            atomicAdd(&hist[d >> BSH], 1);
        }
        __syncthreads();
        if (t < NBK) H[r * NBK + t] = hist[t];
        __syncthreads();
    }
}

// Per-bucket scan over rounds (196 blocks in parallel):
// S2[r][b] = sum_{r'<r} H[r'][b]  (within-bucket prefix), tot[b] = bucket total.
__global__ __launch_bounds__(256) void scan_rounds_kernel(
    const int* __restrict__ H, int* __restrict__ S2, int* __restrict__ tot,
    int R, int NBK)
{
    __shared__ int part[256];
    const int b = blockIdx.x;
    const int t = threadIdx.x;
    const int C = (R + 255) / 256;
    int r0 = t * C, r1 = min(R, r0 + C);
    int s = 0;
    for (int r = r0; r < r1; ++r) s += H[r * NBK + b];
    part[t] = s;
    __syncthreads();
    for (int off = 1; off < 256; off <<= 1) {
        int v = (t >= off) ? part[t - off] : 0;
        __syncthreads();
        part[t] += v;
        __syncthreads();
    }
    int run = (t > 0) ? part[t - 1] : 0;
    for (int r = r0; r < r1; ++r) {
        int h = H[r * NBK + b];
        S2[r * NBK + b] = run;
        run += h;
    }
    if (t == 255) tot[b] = part[255];
}

// Exclusive scan of bucket totals -> base[b]. One block; NBK <= 256.
__global__ __launch_bounds__(256) void scan_tot_kernel(
    const int* __restrict__ tot, int* __restrict__ base, int NBK)
{
    __shared__ int s[256];
    int t = threadIdx.x;
    int v = (t < NBK) ? tot[t] : 0;
    s[t] = v;
    __syncthreads();
    for (int off = 1; off < 256; off <<= 1) {
        int u = (t >= off) ? s[t - off] : 0;
        __syncthreads();
        s[t] += u;
        __syncthreads();
    }
    if (t < NBK) base[t] = s[t] - v;
}

// A1: scatter edges into bucket-grouped pbuf at precomputed offsets.
// pbuf entry = (src << BSH) | (dst & (BW-1)).  src < 2^17, fits in 23+9 bits.
__global__ __launch_bounds__(256) void partition_kernel(
    const int* __restrict__ adj, const int* __restrict__ S2,
    const int* __restrict__ base, int* __restrict__ pbuf,
    int E, int N, int R, int NBK)
{
    __shared__ int lcur[256];
    const int t = threadIdx.x;
    const int ET = E + N;
    for (int r = blockIdx.x; r < R; r += gridDim.x) {
        if (t < NBK) lcur[t] = base[t] + S2[r * NBK + t];
        __syncthreads();
        int b0 = r * CH;
        for (int i = 0; i < CH / 256; ++i) {
            int e = b0 + i * 256 + t;
            if (e >= ET) break;
            int s, d;
            if (e < E) { d = adj[E + e]; s = adj[e]; }
            else       { s = d = e - E; }
            int b = d >> BSH;
            int pos = atomicAdd(&lcur[b], 1);
            pbuf[pos] = (s << BSH) | (d & (BW - 1));
        }
        __syncthreads();
    }
}

// B: one WG per bucket. LDS hist over 512 local nodes + LDS scan ->
// row_ptr window AND node-grouped col_idx, all inside a ~35KB L2-local window.
__global__ __launch_bounds__(256) void csr_build_kernel(
    const int* __restrict__ base, const int* __restrict__ tot,
    const int* __restrict__ pbuf,
    int* __restrict__ row_ptr, int* __restrict__ col_idx, int E, int N, int NBK)
{
    __shared__ int offA[BW];
    __shared__ int lcur[BW];
    const int b = blockIdx.x;
    const int t = threadIdx.x;
    const int node0 = b << BSH;
    const int nn = min(BW, N - node0);
    const int ET = E + N;
    const int segbeg = base[b];
    const int segend = segbeg + tot[b];

    offA[t] = 0; offA[t + 256] = 0;
    __syncthreads();
    for (int i = segbeg + t; i < segend; i += 256)
        atomicAdd(&offA[pbuf[i] & (BW - 1)], 1);
    __syncthreads();
    // inclusive Hillis-Steele scan over 512 elements (2 per thread)
    for (int off = 1; off < BW; off <<= 1) {
        int i1 = t + 256;
        int v0 = (t >= off) ? offA[t - off] : 0;
        int v1 = (i1 >= off) ? offA[i1 - off] : 0;
        __syncthreads();
        offA[t] += v0; offA[i1] += v1;
        __syncthreads();
    }
    if (t < nn) {
        int ex = t ? offA[t - 1] : 0;
        row_ptr[node0 + t] = segbeg + ex;
        lcur[t] = segbeg + ex;
    }
    int i2 = t + 256;
    if (i2 < nn) {
        int ex = offA[i2 - 1];
        row_ptr[node0 + i2] = segbeg + ex;
        lcur[i2] = segbeg + ex;
    }
    if (b == NBK - 1 && t == 0) row_ptr[N] = ET;
    __syncthreads();
    for (int i = segbeg + t; i < segend; i += 256) {
        int p = pbuf[i];
        int pos = atomicAdd(&lcur[p & (BW - 1)], 1);
        col_idx[pos] = p >> BSH;
    }
}

// ================= dense pieces =================

__device__ __forceinline__ unsigned short f2bf(float f)
{
    union { __hip_bfloat16 b; unsigned short u; } v;
    v.b = __float2bfloat16(f);
    return v.u;
}

// Pre-pack W into MFMA B-fragment order, bf16.
// Fragment f = s*4 + t  (s = K-step of 32, t = 16-col tile).
// lane l (0..63), elem i (0..7):  k = 32*s + 8*(l/16) + i,  n = 16*t + (l%16).
__global__ __launch_bounds__(256) void prep_wfrag_kernel(
    const float* __restrict__ W, unsigned short* __restrict__ wf, int K)
{
    int total = K * 64;                  // (K/32)*4 frags * 64 lanes * 8 elems
    int idx = blockIdx.x * 256 + threadIdx.x;
    if (idx >= total) return;
    int i = idx & 7;
    int l = (idx >> 3) & 63;
    int f = idx >> 9;
    int s = f >> 2, tt = f & 3;
    int k = 32 * s + 8 * (l >> 4) + i;
    int n = 16 * tt + (l & 15);
    wf[idx] = f2bf(W[k * 64 + n]);
}

// MFMA GEMM + alpha:  h = bf16(X @ W); as[n] = (h . a_src)*log2e; ad likewise.
// 4 waves/block, each wave owns 16 rows x 64 cols (4 col-tiles of 16x16 MFMA).
// X is split hi+lo bf16 (2 MFMAs per tile) -> A-side error ~2^-16 relative.
// as_/ad_ are pre-scaled by log2(e) so the aggregate can use exp2 directly
// (leaky_relu is positively homogeneous: exp(leaky(x)) == exp2(leaky(x*log2e))).
template<int K>
__global__ __launch_bounds__(256) void gemm_alpha_mfma(
    const float* __restrict__ X, const unsigned short* __restrict__ wf,
    const float* __restrict__ a_src, const float* __restrict__ a_dst,
    __hip_bfloat16* __restrict__ h, float* __restrict__ as_, float* __restrict__ ad_,
    int N, int nChunks)
{
    constexpr int S = K / 32;
    const int t = threadIdx.x;
    const int wave = t >> 6, lane = t & 63;
    const int g = lane >> 4, c = lane & 15;

    // B fragments: S*4 frags, 8 bf16 each (4 VGPRs) -> coalesced 16B loads
    short8 bf[S * 4];
#pragma unroll
    for (int f = 0; f < S * 4; ++f)
        bf[f] = *(const short8*)(wf + ((size_t)(f * 64 + lane)) * 8);

    float asr[4], adr[4];
#pragma unroll
    for (int tt = 0; tt < 4; ++tt) {
        asr[tt] = a_src[16 * tt + c];
        adr[tt] = a_dst[16 * tt + c];
    }

    for (int chunk = blockIdx.x; chunk < nChunks; chunk += gridDim.x) {
        const int r0 = chunk * 64 + wave * 16;
        const int arow = r0 + c;                 // row this lane loads for A
        const bool rv = arow < N;
        const float* xr = X + (size_t)arow * K;

        f32x4 acc[4];
#pragma unroll
        for (int tt = 0; tt < 4; ++tt) acc[tt] = (f32x4){0.f, 0.f, 0.f, 0.f};

#pragma unroll
        for (int s = 0; s < S; ++s) {
            // lane reads X[arow][32s + 8g .. 32s + 8g + 7]
            float4 x0 = make_float4(0.f, 0.f, 0.f, 0.f);
            float4 x1 = make_float4(0.f, 0.f, 0.f, 0.f);
            if (rv) {
                const float4* p = (const float4*)(xr + 32 * s + 8 * g);
                x0 = p[0]; x1 = p[1];
            }
            float xs[8] = {x0.x, x0.y, x0.z, x0.w, x1.x, x1.y, x1.z, x1.w};
            // hi = truncate-to-bf16, lo = truncate(x - hi): exact split to ~2^-16
            union { short8 v; unsigned u[4]; } ah, al;
#pragma unroll
            for (int p2 = 0; p2 < 4; ++p2) {
                unsigned u0 = __float_as_uint(xs[2 * p2]);
                unsigned u1 = __float_as_uint(xs[2 * p2 + 1]);
                ah.u[p2] = (u0 >> 16) | (u1 & 0xffff0000u);
                float h0 = __uint_as_float(u0 & 0xffff0000u);
                float h1 = __uint_as_float(u1 & 0xffff0000u);
                unsigned l0 = __float_as_uint(xs[2 * p2] - h0);
                unsigned l1 = __float_as_uint(xs[2 * p2 + 1] - h1);
                al.u[p2] = (l0 >> 16) | (l1 & 0xffff0000u);
            }
#pragma unroll
            for (int tt = 0; tt < 4; ++tt) {
                acc[tt] = __builtin_amdgcn_mfma_f32_16x16x32_bf16(
                    ah.v, bf[s * 4 + tt], acc[tt], 0, 0, 0);
                acc[tt] = __builtin_amdgcn_mfma_f32_16x16x32_bf16(
                    al.v, bf[s * 4 + tt], acc[tt], 0, 0, 0);
            }
        }

        // epilogue: D layout col = c + 16*tt, row = r0 + 4*g + i  [measured m89/m91]
#pragma unroll
        for (int i = 0; i < 4; ++i) {
            const int ri = r0 + 4 * g + i;
            float va = 0.f, vd = 0.f;
#pragma unroll
            for (int tt = 0; tt < 4; ++tt) {
                float v = acc[tt][i];
                va += v * asr[tt];
                vd += v * adr[tt];
                if (ri < N) h[(size_t)ri * 64 + 16 * tt + c] = __float2bfloat16(v);
            }
#pragma unroll
            for (int off = 8; off >= 1; off >>= 1) {
                va += __shfl_xor(va, off, 16);
                vd += __shfl_xor(vd, off, 16);
            }
            if (c == 0 && ri < N) { as_[ri] = va * LOG2E; ad_[ri] = vd * LOG2E; }
        }
    }
}

// Fused softmax+aggregate: one wave per dst node.
// 8 subs x 8 lanes; each lane loads 16B (8 bf16) of the h row -> VMEM insts
// per edge halved vs ushort4 layout. Main loop = 16 edges (2 per sub),
// tail = masked 8-edge windows. as_/ad_ pre-scaled by log2e -> exp2 direct.
__global__ __launch_bounds__(256) void gat_aggregate_kernel(
    const int* __restrict__ row_ptr, const int* __restrict__ col_idx,
    const float* __restrict__ as_, const float* __restrict__ ad_,
    const __hip_bfloat16* __restrict__ h, const float* __restrict__ b,
    float* __restrict__ out, int N, int do_elu)
{
    int node = blockIdx.x * 4 + (threadIdx.x >> 6);
    int lane = threadIdx.x & 63;
    int sub = lane >> 3, q = lane & 7;
    if (node >= N) return;
    int beg = row_ptr[node], end = row_ptr[node + 1];
    float ad = ad_[node];                // pre-scaled by log2e
    float acc[8] = {0.f, 0.f, 0.f, 0.f, 0.f, 0.f, 0.f, 0.f};
    float psum = 0.f;

    const char* cbp = (const char*)col_idx;
    const char* abp = (const char*)as_;
    const char* hbp = (const char*)h;
    const unsigned qb = (unsigned)q * 16u;

    int base = beg;
    unsigned co = (unsigned)(beg + sub) * 4u;
    // main loop: full 16-edge windows (2 edges per sub), no bounds checks
    for (; base + 16 <= end; base += 16, co += 64u) {
        int s0 = *(const int*)(cbp + co);
        int s1 = *(const int*)(cbp + (co + 32u));
        float x0 = *(const float*)(abp + ((unsigned)s0 << 2)) + ad;
        float x1 = *(const float*)(abp + ((unsigned)s1 << 2)) + ad;
        uint4 u0 = *(const uint4*)(hbp + (((unsigned)s0 << 7) + qb));
        uint4 u1 = *(const uint4*)(hbp + (((unsigned)s1 << 7) + qb));
        x0 = fmaxf(x0, NEG_SLOPE * x0);
        x1 = fmaxf(x1, NEG_SLOPE * x1);
        float p0 = __builtin_amdgcn_exp2f(x0);
        float p1 = __builtin_amdgcn_exp2f(x1);
        psum += p0 + p1;
        unsigned w;
        w = u0.x; acc[0] += p0 * __uint_as_float(w << 16); acc[1] += p0 * __uint_as_float(w & 0xffff0000u);
        w = u0.y; acc[2] += p0 * __uint_as_float(w << 16); acc[3] += p0 * __uint_as_float(w & 0xffff0000u);
        w = u0.z; acc[4] += p0 * __uint_as_float(w << 16); acc[5] += p0 * __uint_as_float(w & 0xffff0000u);
        w = u0.w; acc[6] += p0 * __uint_as_float(w << 16); acc[7] += p0 * __uint_as_float(w & 0xffff0000u);
        w = u1.x; acc[0] += p1 * __uint_as_float(w << 16); acc[1] += p1 * __uint_as_float(w & 0xffff0000u);
        w = u1.y; acc[2] += p1 * __uint_as_float(w << 16); acc[3] += p1 * __uint_as_float(w & 0xffff0000u);
        w = u1.z; acc[4] += p1 * __uint_as_float(w << 16); acc[5] += p1 * __uint_as_float(w & 0xffff0000u);
        w = u1.w; acc[6] += p1 * __uint_as_float(w << 16); acc[7] += p1 * __uint_as_float(w & 0xffff0000u);
    }
    // tail: masked 8-edge windows (at most 2)
    for (; base < end; base += 8, co += 32u) {
        int e0 = base + sub;
        bool v0 = e0 < end;
        unsigned c0 = (unsigned)(v0 ? e0 : end - 1) * 4u;
        int s0 = *(const int*)(cbp + c0);
        float x0 = *(const float*)(abp + ((unsigned)s0 << 2)) + ad;
        uint4 u0 = *(const uint4*)(hbp + (((unsigned)s0 << 7) + qb));
        x0 = fmaxf(x0, NEG_SLOPE * x0);
        float p0 = v0 ? __builtin_amdgcn_exp2f(x0) : 0.f;
        psum += p0;
        unsigned w;
        w = u0.x; acc[0] += p0 * __uint_as_float(w << 16); acc[1] += p0 * __uint_as_float(w & 0xffff0000u);
        w = u0.y; acc[2] += p0 * __uint_as_float(w << 16); acc[3] += p0 * __uint_as_float(w & 0xffff0000u);
        w = u0.z; acc[4] += p0 * __uint_as_float(w << 16); acc[5] += p0 * __uint_as_float(w & 0xffff0000u);
        w = u0.w; acc[6] += p0 * __uint_as_float(w << 16); acc[7] += p0 * __uint_as_float(w & 0xffff0000u);
    }
#pragma unroll
    for (int off = 8; off <= 32; off <<= 1) {
        psum += __shfl_xor(psum, off, 64);
#pragma unroll
        for (int j = 0; j < 8; ++j) acc[j] += __shfl_xor(acc[j], off, 64);
    }
    if (sub == 0) {
        float inv = 1.f / psum;
        const float* bq = b + q * 8;
        float4 b0 = *(const float4*)bq;
        float4 b1 = *(const float4*)(bq + 4);
        float v[8];
        v[0] = acc[0] * inv + b0.x; v[1] = acc[1] * inv + b0.y;
        v[2] = acc[2] * inv + b0.z; v[3] = acc[3] * inv + b0.w;
        v[4] = acc[4] * inv + b1.x; v[5] = acc[5] * inv + b1.y;
        v[6] = acc[6] * inv + b1.z; v[7] = acc[7] * inv + b1.w;
        if (do_elu) {
#pragma unroll
            for (int j = 0; j < 8; ++j)
                v[j] = v[j] > 0.f ? v[j] : (__expf(v[j]) - 1.f);
        }
        float* op = out + (size_t)node * 64 + q * 8;
        ((float4*)op)[0] = make_float4(v[0], v[1], v[2], v[3]);
        ((float4*)op)[1] = make_float4(v[4], v[5], v[6], v[7]);
    }
}

// logits[n][c] = x[n]·cW[:,c] + cb[c]
__global__ __launch_bounds__(256) void classifier_kernel(
    const float* __restrict__ x, const float* __restrict__ cw,
    const float* __restrict__ cb, float* __restrict__ out, int N)
{
    int i = blockIdx.x * blockDim.x + threadIdx.x;
    if (i >= N * 16) return;
    int n = i >> 4, c = i & 15;
    const float4* xr = (const float4*)(x + (size_t)n * 64);
    float acc = cb[c];
#pragma unroll
    for (int j4 = 0; j4 < 16; ++j4) {
        float4 xv = xr[j4];
        acc += xv.x * cw[(j4 * 4 + 0) * 16 + c];
        acc += xv.y * cw[(j4 * 4 + 1) * 16 + c];
        acc += xv.z * cw[(j4 * 4 + 2) * 16 + c];
        acc += xv.w * cw[(j4 * 4 + 3) * 16 + c];
    }
    out[i] = acc;
}

extern "C" void kernel_launch(void* const* d_in, const int* in_sizes, int n_in,
                              void* d_out, int out_size, void* d_ws, size_t ws_size,
                              hipStream_t stream)
{
    const float* X    = (const float*)d_in[0];
    const int*   adj  = (const int*)d_in[1];
    const float* W1   = (const float*)d_in[2];
    const float* a_s1 = (const float*)d_in[3];
    const float* a_d1 = (const float*)d_in[4];
    const float* b1   = (const float*)d_in[5];
    const float* W2   = (const float*)d_in[6];
    const float* a_s2 = (const float*)d_in[7];
    const float* a_d2 = (const float*)d_in[8];
    const float* b2   = (const float*)d_in[9];
    const float* cW   = (const float*)d_in[10];
    const float* cb   = (const float*)d_in[11];

    const int N   = in_sizes[0] / 128;
    const int E   = in_sizes[1] / 2;
    const int ET  = E + N;
    const int R   = (ET + CH - 1) / CH;           // partition rounds
    const int NBK = (N + BW - 1) >> BSH;          // buckets (<=256)

    __hip_bfloat16* A = (__hip_bfloat16*)d_ws;        // h (bf16), N*64
    float* B       = (float*)(A + (size_t)N * 64);    // layer1 x, N*64 f32
    float* asb     = B + (size_t)N * 64;              // N
    float* adb     = asb + N;                         // N
    int*   row_ptr = (int*)(adb + N);                 // N+1
    int*   col_idx = row_ptr + (N + 1);               // ET
    int*   pbuf    = col_idx + ET;                    // ET
    int*   H       = pbuf + ET;                       // R*NBK
    int*   S2      = H + R * NBK;                     // R*NBK
    int*   tot     = S2 + R * NBK;                    // NBK
    int*   base    = tot + NBK;                       // NBK

    // W fragment buffers alias pbuf (dead after csr_build; preps run after it)
    uintptr_t wp = ((uintptr_t)pbuf + 15) & ~(uintptr_t)15;
    unsigned short* wf1 = (unsigned short*)wp;        // 128*64 ushort = 16KB
    unsigned short* wf2 = wf1 + 128 * 64;             // 64*64 ushort = 8KB

    const int T = 256;
    const int aggBlocks  = (N + 3) / 4;
    const int nChunks    = (N + 63) / 64;
    const int gemmBlocks = nChunks < 512 ? nChunks : 512;

    // ---- radix CSR build (once, reused by both layers) ----
    bucket_hist_kernel<<<PGRID, T, 0, stream>>>(adj, H, E, N, R, NBK);
    scan_rounds_kernel<<<NBK, T, 0, stream>>>(H, S2, tot, R, NBK);
    scan_tot_kernel<<<1, T, 0, stream>>>(tot, base, NBK);
    partition_kernel<<<PGRID, T, 0, stream>>>(adj, S2, base, pbuf, E, N, R, NBK);
    csr_build_kernel<<<NBK, T, 0, stream>>>(base, tot, pbuf, row_ptr, col_idx, E, N, NBK);

    // ---- pack W fragments (after csr_build: pbuf space is dead now) ----
    prep_wfrag_kernel<<<(128 * 64 + 255) / 256, T, 0, stream>>>(W1, wf1, 128);
    prep_wfrag_kernel<<<(64 * 64 + 255) / 256, T, 0, stream>>>(W2, wf2, 64);

    // ---- layer 1 ----
    gemm_alpha_mfma<128><<<gemmBlocks, T, 0, stream>>>(
        X, wf1, a_s1, a_d1, A, asb, adb, N, nChunks);
    gat_aggregate_kernel<<<aggBlocks, T, 0, stream>>>(
        row_ptr, col_idx, asb, adb, A, b1, B, N, 1);

    // ---- layer 2 (x written straight into d_out tail) ----
    float* out  = (float*)d_out;
    float* xout = out + (size_t)N * 16;
    gemm_alpha_mfma<64><<<gemmBlocks, T, 0, stream>>>(
        B, wf2, a_s2, a_d2, A, asb, adb, N, nChunks);
    gat_aggregate_kernel<<<aggBlocks, T, 0, stream>>>(
        row_ptr, col_idx, asb, adb, A, b2, xout, N, 0);

    // ---- classifier ----
    classifier_kernel<<<(N * 16 + T - 1) / T, T, 0, stream>>>(
        xout, cW, cb, out, N);
}

// Round 4
// 299.568 us; speedup vs baseline: 1.2983x; 1.0425x over previous
//
#include <hip/hip_runtime.h>
#include <hip/hip_bf16.h>

#define NEG_SLOPE 0.2f
#define LOG2E 1.4426950408889634f
#define BSH 9                    // 512 dst nodes per bucket
#define BW  (1 << BSH)
#define CH  4096                 // edges per partition round
#define PGRID 256                // workgroups for A0/A1

typedef short short8 __attribute__((ext_vector_type(8)));
typedef float f32x4 __attribute__((ext_vector_type(4)));

// ================= radix CSR build (no global atomics) =================

// A0: per-round bucket histogram. H[r*NBK + b] = #edges of round r in bucket b.
__global__ __launch_bounds__(256) void bucket_hist_kernel(
    const int* __restrict__ adj, int* __restrict__ H, int E, int N, int R, int NBK)
{
    __shared__ int hist[256];
    const int t = threadIdx.x;
    const int ET = E + N;
    for (int r = blockIdx.x; r < R; r += gridDim.x) {
        hist[t] = 0;
        __syncthreads();
        int base = r * CH;
        for (int i = 0; i < CH / 256; ++i) {
            int e = base + i * 256 + t;
            if (e >= ET) break;
            int d = (e < E) ? adj[E + e] : (e - E);
            atomicAdd(&hist[d >> BSH], 1);
        }
        __syncthreads();
        if (t < NBK) H[r * NBK + t] = hist[t];
        __syncthreads();
    }
}

// Per-bucket scan over rounds (196 blocks in parallel):
// S2[r][b] = sum_{r'<r} H[r'][b]  (within-bucket prefix), tot[b] = bucket total.
__global__ __launch_bounds__(256) void scan_rounds_kernel(
    const int* __restrict__ H, int* __restrict__ S2, int* __restrict__ tot,
    int R, int NBK)
{
    __shared__ int part[256];
    const int b = blockIdx.x;
    const int t = threadIdx.x;
    const int C = (R + 255) / 256;
    int r0 = t * C, r1 = min(R, r0 + C);
    int s = 0;
    for (int r = r0; r < r1; ++r) s += H[r * NBK + b];
    part[t] = s;
    __syncthreads();
    for (int off = 1; off < 256; off <<= 1) {
        int v = (t >= off) ? part[t - off] : 0;
        __syncthreads();
        part[t] += v;
        __syncthreads();
    }
    int run = (t > 0) ? part[t - 1] : 0;
    for (int r = r0; r < r1; ++r) {
        int h = H[r * NBK + b];
        S2[r * NBK + b] = run;
        run += h;
    }
    if (t == 255) tot[b] = part[255];
}

// Exclusive scan of bucket totals -> base[b]. One block; NBK <= 256.
__global__ __launch_bounds__(256) void scan_tot_kernel(
    const int* __restrict__ tot, int* __restrict__ base, int NBK)
{
    __shared__ int s[256];
    int t = threadIdx.x;
    int v = (t < NBK) ? tot[t] : 0;
    s[t] = v;
    __syncthreads();
    for (int off = 1; off < 256; off <<= 1) {
        int u = (t >= off) ? s[t - off] : 0;
        __syncthreads();
        s[t] += u;
        __syncthreads();
    }
    if (t < NBK) base[t] = s[t] - v;
}

// A1: scatter edges into bucket-grouped pbuf at precomputed offsets.
// pbuf entry = (src << BSH) | (dst & (BW-1)).  src < 2^17, fits in 23+9 bits.
__global__ __launch_bounds__(256) void partition_kernel(
    const int* __restrict__ adj, const int* __restrict__ S2,
    const int* __restrict__ base, int* __restrict__ pbuf,
    int E, int N, int R, int NBK)
{
    __shared__ int lcur[256];
    const int t = threadIdx.x;
    const int ET = E + N;
    for (int r = blockIdx.x; r < R; r += gridDim.x) {
        if (t < NBK) lcur[t] = base[t] + S2[r * NBK + t];
        __syncthreads();
        int b0 = r * CH;
        for (int i = 0; i < CH / 256; ++i) {
            int e = b0 + i * 256 + t;
            if (e >= ET) break;
            int s, d;
            if (e < E) { d = adj[E + e]; s = adj[e]; }
            else       { s = d = e - E; }
            int b = d >> BSH;
            int pos = atomicAdd(&lcur[b], 1);
            pbuf[pos] = (s << BSH) | (d & (BW - 1));
        }
        __syncthreads();
    }
}

// B: one WG per bucket. LDS hist over 512 local nodes + LDS scan ->
// row_ptr window AND node-grouped col_idx, all inside a ~35KB L2-local window.
__global__ __launch_bounds__(256) void csr_build_kernel(
    const int* __restrict__ base, const int* __restrict__ tot,
    const int* __restrict__ pbuf,
    int* __restrict__ row_ptr, int* __restrict__ col_idx, int E, int N, int NBK)
{
    __shared__ int offA[BW];
    __shared__ int lcur[BW];
    const int b = blockIdx.x;
    const int t = threadIdx.x;
    const int node0 = b << BSH;
    const int nn = min(BW, N - node0);
    const int ET = E + N;
    const int segbeg = base[b];
    const int segend = segbeg + tot[b];

    offA[t] = 0; offA[t + 256] = 0;
    __syncthreads();
    for (int i = segbeg + t; i < segend; i += 256)
        atomicAdd(&offA[pbuf[i] & (BW - 1)], 1);
    __syncthreads();
    // inclusive Hillis-Steele scan over 512 elements (2 per thread)
    for (int off = 1; off < BW; off <<= 1) {
        int i1 = t + 256;
        int v0 = (t >= off) ? offA[t - off] : 0;
        int v1 = (i1 >= off) ? offA[i1 - off] : 0;
        __syncthreads();
        offA[t] += v0; offA[i1] += v1;
        __syncthreads();
    }
    if (t < nn) {
        int ex = t ? offA[t - 1] : 0;
        row_ptr[node0 + t] = segbeg + ex;
        lcur[t] = segbeg + ex;
    }
    int i2 = t + 256;
    if (i2 < nn) {
        int ex = offA[i2 - 1];
        row_ptr[node0 + i2] = segbeg + ex;
        lcur[i2] = segbeg + ex;
    }
    if (b == NBK - 1 && t == 0) row_ptr[N] = ET;
    __syncthreads();
    for (int i = segbeg + t; i < segend; i += 256) {
        int p = pbuf[i];
        int pos = atomicAdd(&lcur[p & (BW - 1)], 1);
        col_idx[pos] = p >> BSH;
    }
}

// ================= dense pieces =================

__device__ __forceinline__ unsigned short f2bf(float f)
{
    union { __hip_bfloat16 b; unsigned short u; } v;
    v.b = __float2bfloat16(f);
    return v.u;
}

// Pre-pack W into MFMA B-fragment order, bf16.
// Fragment f = s*4 + t  (s = K-step of 32, t = 16-col tile).
// lane l (0..63), elem i (0..7):  k = 32*s + 8*(l/16) + i,  n = 16*t + (l%16).
__global__ __launch_bounds__(256) void prep_wfrag_kernel(
    const float* __restrict__ W, unsigned short* __restrict__ wf, int K)
{
    int total = K * 64;                  // (K/32)*4 frags * 64 lanes * 8 elems
    int idx = blockIdx.x * 256 + threadIdx.x;
    if (idx >= total) return;
    int i = idx & 7;
    int l = (idx >> 3) & 63;
    int f = idx >> 9;
    int s = f >> 2, tt = f & 3;
    int k = 32 * s + 8 * (l >> 4) + i;
    int n = 16 * tt + (l & 15);
    wf[idx] = f2bf(W[k * 64 + n]);
}

// MFMA GEMM + alpha:  h = bf16(X @ W); as[n] = (h . a_src)*log2e; ad likewise.
// 4 waves/block, each wave owns 16 rows x 64 cols (4 col-tiles of 16x16 MFMA).
// X is split hi+lo bf16 (2 MFMAs per tile) -> A-side error ~2^-16 relative.
// as_/ad_ are pre-scaled by log2(e) so the aggregate can use exp2 directly
// (leaky_relu is positively homogeneous: exp(leaky(x)) == exp2(leaky(x*log2e))).
template<int K>
__global__ __launch_bounds__(256) void gemm_alpha_mfma(
    const float* __restrict__ X, const unsigned short* __restrict__ wf,
    const float* __restrict__ a_src, const float* __restrict__ a_dst,
    __hip_bfloat16* __restrict__ h, float* __restrict__ as_, float* __restrict__ ad_,
    int N, int nChunks)
{
    constexpr int S = K / 32;
    const int t = threadIdx.x;
    const int wave = t >> 6, lane = t & 63;
    const int g = lane >> 4, c = lane & 15;

    // B fragments: S*4 frags, 8 bf16 each (4 VGPRs) -> coalesced 16B loads
    short8 bf[S * 4];
#pragma unroll
    for (int f = 0; f < S * 4; ++f)
        bf[f] = *(const short8*)(wf + ((size_t)(f * 64 + lane)) * 8);

    float asr[4], adr[4];
#pragma unroll
    for (int tt = 0; tt < 4; ++tt) {
        asr[tt] = a_src[16 * tt + c];
        adr[tt] = a_dst[16 * tt + c];
    }

    for (int chunk = blockIdx.x; chunk < nChunks; chunk += gridDim.x) {
        const int r0 = chunk * 64 + wave * 16;
        const int arow = r0 + c;                 // row this lane loads for A
        const bool rv = arow < N;
        const float* xr = X + (size_t)arow * K;

        f32x4 acc[4];
#pragma unroll
        for (int tt = 0; tt < 4; ++tt) acc[tt] = (f32x4){0.f, 0.f, 0.f, 0.f};

#pragma unroll
        for (int s = 0; s < S; ++s) {
            // lane reads X[arow][32s + 8g .. 32s + 8g + 7]
            float4 x0 = make_float4(0.f, 0.f, 0.f, 0.f);
            float4 x1 = make_float4(0.f, 0.f, 0.f, 0.f);
            if (rv) {
                const float4* p = (const float4*)(xr + 32 * s + 8 * g);
                x0 = p[0]; x1 = p[1];
            }
            float xs[8] = {x0.x, x0.y, x0.z, x0.w, x1.x, x1.y, x1.z, x1.w};
            // hi = truncate-to-bf16, lo = truncate(x - hi): exact split to ~2^-16
            union { short8 v; unsigned u[4]; } ah, al;
#pragma unroll
            for (int p2 = 0; p2 < 4; ++p2) {
                unsigned u0 = __float_as_uint(xs[2 * p2]);
                unsigned u1 = __float_as_uint(xs[2 * p2 + 1]);
                ah.u[p2] = (u0 >> 16) | (u1 & 0xffff0000u);
                float h0 = __uint_as_float(u0 & 0xffff0000u);
                float h1 = __uint_as_float(u1 & 0xffff0000u);
                unsigned l0 = __float_as_uint(xs[2 * p2] - h0);
                unsigned l1 = __float_as_uint(xs[2 * p2 + 1] - h1);
                al.u[p2] = (l0 >> 16) | (l1 & 0xffff0000u);
            }
#pragma unroll
            for (int tt = 0; tt < 4; ++tt) {
                acc[tt] = __builtin_amdgcn_mfma_f32_16x16x32_bf16(
                    ah.v, bf[s * 4 + tt], acc[tt], 0, 0, 0);
                acc[tt] = __builtin_amdgcn_mfma_f32_16x16x32_bf16(
                    al.v, bf[s * 4 + tt], acc[tt], 0, 0, 0);
            }
        }

        // epilogue: D layout col = c + 16*tt, row = r0 + 4*g + i  [measured m89/m91]
#pragma unroll
        for (int i = 0; i < 4; ++i) {
            const int ri = r0 + 4 * g + i;
            float va = 0.f, vd = 0.f;
#pragma unroll
            for (int tt = 0; tt < 4; ++tt) {
                float v = acc[tt][i];
                va += v * asr[tt];
                vd += v * adr[tt];
                if (ri < N) h[(size_t)ri * 64 + 16 * tt + c] = __float2bfloat16(v);
            }
#pragma unroll
            for (int off = 8; off >= 1; off >>= 1) {
                va += __shfl_xor(va, off, 16);
                vd += __shfl_xor(vd, off, 16);
            }
            if (c == 0 && ri < N) { as_[ri] = va * LOG2E; ad_[ri] = vd * LOG2E; }
        }
    }
}

// Fused softmax+aggregate: ONE 8-LANE SUB PER NODE (8 nodes per wave).
// Each lane owns 8 fixed output dims -> acc needs NO cross-lane reduce;
// psum is computed redundantly by the sub's 8 lanes -> NO reduce either.
// 2 edges per iteration; per-sub loop bounds handled by exec mask.
// h row read = 8 lanes x 16B contiguous = one 128B line per edge (unchanged).
__global__ __launch_bounds__(256) void gat_aggregate_kernel(
    const int* __restrict__ row_ptr, const int* __restrict__ col_idx,
    const float* __restrict__ as_, const float* __restrict__ ad_,
    const __hip_bfloat16* __restrict__ h, const float* __restrict__ b,
    float* __restrict__ out, int N, int do_elu)
{
    const int wave = threadIdx.x >> 6, lane = threadIdx.x & 63;
    const int sub = lane >> 3, q = lane & 7;
    const int node = blockIdx.x * 32 + wave * 8 + sub;
    if (node >= N) return;
    const int beg = row_ptr[node], end = row_ptr[node + 1];
    const float ad = ad_[node];          // pre-scaled by log2e
    float acc[8] = {0.f, 0.f, 0.f, 0.f, 0.f, 0.f, 0.f, 0.f};
    float psum = 0.f;

    const char* cbp = (const char*)col_idx;
    const char* abp = (const char*)as_;
    const char* hbp = (const char*)h;
    const unsigned qb = (unsigned)q * 16u;

    unsigned co = (unsigned)beg * 4u;
    for (int i = beg; i < end; i += 2, co += 8u) {
        const bool v1 = (i + 1) < end;
        int s0 = *(const int*)(cbp + co);
        int s1 = *(const int*)(cbp + (v1 ? co + 4u : co));
        float x0 = *(const float*)(abp + ((unsigned)s0 << 2)) + ad;
        float x1 = *(const float*)(abp + ((unsigned)s1 << 2)) + ad;
        uint4 u0 = *(const uint4*)(hbp + (((unsigned)s0 << 7) + qb));
        uint4 u1 = *(const uint4*)(hbp + (((unsigned)s1 << 7) + qb));
        x0 = fmaxf(x0, NEG_SLOPE * x0);
        x1 = fmaxf(x1, NEG_SLOPE * x1);
        float p0 = __builtin_amdgcn_exp2f(x0);
        float p1 = v1 ? __builtin_amdgcn_exp2f(x1) : 0.f;
        psum += p0 + p1;
        unsigned w;
        w = u0.x; acc[0] += p0 * __uint_as_float(w << 16); acc[1] += p0 * __uint_as_float(w & 0xffff0000u);
        w = u0.y; acc[2] += p0 * __uint_as_float(w << 16); acc[3] += p0 * __uint_as_float(w & 0xffff0000u);
        w = u0.z; acc[4] += p0 * __uint_as_float(w << 16); acc[5] += p0 * __uint_as_float(w & 0xffff0000u);
        w = u0.w; acc[6] += p0 * __uint_as_float(w << 16); acc[7] += p0 * __uint_as_float(w & 0xffff0000u);
        w = u1.x; acc[0] += p1 * __uint_as_float(w << 16); acc[1] += p1 * __uint_as_float(w & 0xffff0000u);
        w = u1.y; acc[2] += p1 * __uint_as_float(w << 16); acc[3] += p1 * __uint_as_float(w & 0xffff0000u);
        w = u1.z; acc[4] += p1 * __uint_as_float(w << 16); acc[5] += p1 * __uint_as_float(w & 0xffff0000u);
        w = u1.w; acc[6] += p1 * __uint_as_float(w << 16); acc[7] += p1 * __uint_as_float(w & 0xffff0000u);
    }

    const float inv = 1.f / psum;
    const float* bq = b + q * 8;
    float4 b0 = *(const float4*)bq;
    float4 b1 = *(const float4*)(bq + 4);
    float v[8];
    v[0] = acc[0] * inv + b0.x; v[1] = acc[1] * inv + b0.y;
    v[2] = acc[2] * inv + b0.z; v[3] = acc[3] * inv + b0.w;
    v[4] = acc[4] * inv + b1.x; v[5] = acc[5] * inv + b1.y;
    v[6] = acc[6] * inv + b1.z; v[7] = acc[7] * inv + b1.w;
    if (do_elu) {
#pragma unroll
        for (int j = 0; j < 8; ++j)
            v[j] = v[j] > 0.f ? v[j] : (__expf(v[j]) - 1.f);
    }
    float* op = out + (size_t)node * 64 + q * 8;
    ((float4*)op)[0] = make_float4(v[0], v[1], v[2], v[3]);
    ((float4*)op)[1] = make_float4(v[4], v[5], v[6], v[7]);
}

// logits[n][c] = x[n]·cW[:,c] + cb[c]
__global__ __launch_bounds__(256) void classifier_kernel(
    const float* __restrict__ x, const float* __restrict__ cw,
    const float* __restrict__ cb, float* __restrict__ out, int N)
{
    int i = blockIdx.x * blockDim.x + threadIdx.x;
    if (i >= N * 16) return;
    int n = i >> 4, c = i & 15;
    const float4* xr = (const float4*)(x + (size_t)n * 64);
    float acc = cb[c];
#pragma unroll
    for (int j4 = 0; j4 < 16; ++j4) {
        float4 xv = xr[j4];
        acc += xv.x * cw[(j4 * 4 + 0) * 16 + c];
        acc += xv.y * cw[(j4 * 4 + 1) * 16 + c];
        acc += xv.z * cw[(j4 * 4 + 2) * 16 + c];
        acc += xv.w * cw[(j4 * 4 + 3) * 16 + c];
    }
    out[i] = acc;
}

extern "C" void kernel_launch(void* const* d_in, const int* in_sizes, int n_in,
                              void* d_out, int out_size, void* d_ws, size_t ws_size,
                              hipStream_t stream)
{
    const float* X    = (const float*)d_in[0];
    const int*   adj  = (const int*)d_in[1];
    const float* W1   = (const float*)d_in[2];
    const float* a_s1 = (const float*)d_in[3];
    const float* a_d1 = (const float*)d_in[4];
    const float* b1   = (const float*)d_in[5];
    const float* W2   = (const float*)d_in[6];
    const float* a_s2 = (const float*)d_in[7];
    const float* a_d2 = (const float*)d_in[8];
    const float* b2   = (const float*)d_in[9];
    const float* cW   = (const float*)d_in[10];
    const float* cb   = (const float*)d_in[11];

    const int N   = in_sizes[0] / 128;
    const int E   = in_sizes[1] / 2;
    const int ET  = E + N;
    const int R   = (ET + CH - 1) / CH;           // partition rounds
    const int NBK = (N + BW - 1) >> BSH;          // buckets (<=256)

    __hip_bfloat16* A = (__hip_bfloat16*)d_ws;        // h (bf16), N*64
    float* B       = (float*)(A + (size_t)N * 64);    // layer1 x, N*64 f32
    float* asb     = B + (size_t)N * 64;              // N
    float* adb     = asb + N;                         // N
    int*   row_ptr = (int*)(adb + N);                 // N+1
    int*   col_idx = row_ptr + (N + 1);               // ET
    int*   pbuf    = col_idx + ET;                    // ET
    int*   H       = pbuf + ET;                       // R*NBK
    int*   S2      = H + R * NBK;                     // R*NBK
    int*   tot     = S2 + R * NBK;                    // NBK
    int*   base    = tot + NBK;                       // NBK

    // W fragment buffers alias pbuf (dead after csr_build; preps run after it)
    uintptr_t wp = ((uintptr_t)pbuf + 15) & ~(uintptr_t)15;
    unsigned short* wf1 = (unsigned short*)wp;        // 128*64 ushort = 16KB
    unsigned short* wf2 = wf1 + 128 * 64;             // 64*64 ushort = 8KB

    const int T = 256;
    const int aggBlocks  = (N + 31) / 32;
    const int nChunks    = (N + 63) / 64;
    const int gemmBlocks = nChunks < 512 ? nChunks : 512;

    // ---- radix CSR build (once, reused by both layers) ----
    bucket_hist_kernel<<<PGRID, T, 0, stream>>>(adj, H, E, N, R, NBK);
    scan_rounds_kernel<<<NBK, T, 0, stream>>>(H, S2, tot, R, NBK);
    scan_tot_kernel<<<1, T, 0, stream>>>(tot, base, NBK);
    partition_kernel<<<PGRID, T, 0, stream>>>(adj, S2, base, pbuf, E, N, R, NBK);
    csr_build_kernel<<<NBK, T, 0, stream>>>(base, tot, pbuf, row_ptr, col_idx, E, N, NBK);

    // ---- pack W fragments (after csr_build: pbuf space is dead now) ----
    prep_wfrag_kernel<<<(128 * 64 + 255) / 256, T, 0, stream>>>(W1, wf1, 128);
    prep_wfrag_kernel<<<(64 * 64 + 255) / 256, T, 0, stream>>>(W2, wf2, 64);

    // ---- layer 1 ----
    gemm_alpha_mfma<128><<<gemmBlocks, T, 0, stream>>>(
        X, wf1, a_s1, a_d1, A, asb, adb, N, nChunks);
    gat_aggregate_kernel<<<aggBlocks, T, 0, stream>>>(
        row_ptr, col_idx, asb, adb, A, b1, B, N, 1);

    // ---- layer 2 (x written straight into d_out tail) ----
    float* out  = (float*)d_out;
    float* xout = out + (size_t)N * 16;
    gemm_alpha_mfma<64><<<gemmBlocks, T, 0, stream>>>(
        B, wf2, a_s2, a_d2, A, asb, adb, N, nChunks);
    gat_aggregate_kernel<<<aggBlocks, T, 0, stream>>>(
        row_ptr, col_idx, asb, adb, A, b2, xout, N, 0);

    // ---- classifier ----
    classifier_kernel<<<(N * 16 + T - 1) / T, T, 0, stream>>>(
        xout, cW, cb, out, N);
}